// Round 3
// baseline (48.593 us; speedup 1.0000x reference)
//
#include <hip/hip_runtime.h>

// out[p,:] = x[p,:] @ W + b  — the reference's sort/gather/scatter permutation
// cancels exactly (out_feats[inverse] with feats = x[indices] is the identity
// permutation). Pure memory-bound elementwise affine.
//
// Round-1 counters: FETCH 49.5 MB (L3 absorbs half the 100 MB input),
// WRITE 101 MB. Output is write-once/never-read -> non-temporal stores keep
// the input L3-resident and cut HBM fetch further.
//
// NOTE: __builtin_nontemporal_store requires a NATIVE clang vector type,
// not HIP's float4 wrapper -> use ext_vector_type(4).

typedef float f32x4 __attribute__((ext_vector_type(4)));

__global__ __launch_bounds__(256) void affine3_kernel(
    const float* __restrict__ x,
    const float* __restrict__ W,
    const float* __restrict__ bias,
    float* __restrict__ out,
    long long ngroups,      // number of 4-point groups (12 floats each)
    long long npoints)      // total points P
{
    const float w00 = W[0], w01 = W[1], w02 = W[2];
    const float w10 = W[3], w11 = W[4], w12 = W[5];
    const float w20 = W[6], w21 = W[7], w22 = W[8];
    const float b0 = bias[0], b1 = bias[1], b2 = bias[2];

    const long long tid    = (long long)blockIdx.x * blockDim.x + threadIdx.x;
    const long long stride = (long long)gridDim.x * blockDim.x;

    const f32x4* __restrict__ xin = reinterpret_cast<const f32x4*>(x);
    f32x4* __restrict__ xout      = reinterpret_cast<f32x4*>(out);

    for (long long g = tid; g < ngroups; g += stride) {
        const long long base = g * 3;
        f32x4 v0 = xin[base + 0];
        f32x4 v1 = xin[base + 1];
        f32x4 v2 = xin[base + 2];

        float p0x = v0.x, p0y = v0.y, p0z = v0.z;
        float p1x = v0.w, p1y = v1.x, p1z = v1.y;
        float p2x = v1.z, p2y = v1.w, p2z = v2.x;
        float p3x = v2.y, p3y = v2.z, p3z = v2.w;

        float o0x = fmaf(p0x, w00, fmaf(p0y, w10, fmaf(p0z, w20, b0)));
        float o0y = fmaf(p0x, w01, fmaf(p0y, w11, fmaf(p0z, w21, b1)));
        float o0z = fmaf(p0x, w02, fmaf(p0y, w12, fmaf(p0z, w22, b2)));

        float o1x = fmaf(p1x, w00, fmaf(p1y, w10, fmaf(p1z, w20, b0)));
        float o1y = fmaf(p1x, w01, fmaf(p1y, w11, fmaf(p1z, w21, b1)));
        float o1z = fmaf(p1x, w02, fmaf(p1y, w12, fmaf(p1z, w22, b2)));

        float o2x = fmaf(p2x, w00, fmaf(p2y, w10, fmaf(p2z, w20, b0)));
        float o2y = fmaf(p2x, w01, fmaf(p2y, w11, fmaf(p2z, w21, b1)));
        float o2z = fmaf(p2x, w02, fmaf(p2y, w12, fmaf(p2z, w22, b2)));

        float o3x = fmaf(p3x, w00, fmaf(p3y, w10, fmaf(p3z, w20, b0)));
        float o3y = fmaf(p3x, w01, fmaf(p3y, w11, fmaf(p3z, w21, b1)));
        float o3z = fmaf(p3x, w02, fmaf(p3y, w12, fmaf(p3z, w22, b2)));

        f32x4 r0 = {o0x, o0y, o0z, o1x};
        f32x4 r1 = {o1y, o1z, o2x, o2y};
        f32x4 r2 = {o2z, o3x, o3y, o3z};

        // Non-temporal: output is never re-read; don't evict the L3-resident
        // input with write allocations.
        __builtin_nontemporal_store(r0, &xout[base + 0]);
        __builtin_nontemporal_store(r1, &xout[base + 1]);
        __builtin_nontemporal_store(r2, &xout[base + 2]);
    }

    for (long long p = ngroups * 4 + tid; p < npoints; p += stride) {
        float px = x[p * 3 + 0], py = x[p * 3 + 1], pz = x[p * 3 + 2];
        float ox = fmaf(px, w00, fmaf(py, w10, fmaf(pz, w20, b0)));
        float oy = fmaf(px, w01, fmaf(py, w11, fmaf(pz, w21, b1)));
        float oz = fmaf(px, w02, fmaf(py, w12, fmaf(pz, w22, b2)));
        __builtin_nontemporal_store(ox, &out[p * 3 + 0]);
        __builtin_nontemporal_store(oy, &out[p * 3 + 1]);
        __builtin_nontemporal_store(oz, &out[p * 3 + 2]);
    }
}

extern "C" void kernel_launch(void* const* d_in, const int* in_sizes, int n_in,
                              void* d_out, int out_size, void* d_ws, size_t ws_size,
                              hipStream_t stream) {
    const float* x    = (const float*)d_in[0];
    const float* W    = (const float*)d_in[1];
    const float* bias = (const float*)d_in[2];
    float* out        = (float*)d_out;

    const long long n       = (long long)in_sizes[0];  // total floats in x
    const long long npoints = n / 3;
    const long long ngroups = npoints / 4;

    const int block = 256;
    long long want = (ngroups + block - 1) / block;
    int grid = (int)(want < 2048 ? (want > 0 ? want : 1) : 2048);

    affine3_kernel<<<grid, block, 0, stream>>>(x, W, bias, out, ngroups, npoints);
}

// Round 4
// 35.040 us; speedup vs baseline: 1.3868x; 1.3868x over previous
//
#include <hip/hip_runtime.h>

// out[p,:] = x[p,:] @ W + b  — the reference's sort/gather/scatter permutation
// cancels exactly. Pure memory-bound elementwise affine.
//
// R1: cached strided stores: FETCH 49.5 MB / WRITE 101 MB, 35.8 us.
// R3: nt + 48B-strided stores: WRITE amplified to 134 MB (partial lines), 48.6 us.
// R4 (this): stage stores through LDS so each wave store instruction is a
// contiguous 1 KB full-line run, THEN nt. Full lines -> no amplification;
// nt -> output doesn't evict the L3-resident input -> FETCH drops.

typedef float f32x4 __attribute__((ext_vector_type(4)));

constexpr int TPB = 256;
constexpr int TILE_F4 = TPB * 3;   // 768 float4 per tile = 1024 points

__global__ __launch_bounds__(TPB) void affine3_kernel(
    const float* __restrict__ x,
    const float* __restrict__ W,
    const float* __restrict__ bias,
    float* __restrict__ out,
    long long ntiles,
    long long npoints)
{
    __shared__ f32x4 lds[TILE_F4];

    const float w00 = W[0], w01 = W[1], w02 = W[2];
    const float w10 = W[3], w11 = W[4], w12 = W[5];
    const float w20 = W[6], w21 = W[7], w22 = W[8];
    const float b0 = bias[0], b1 = bias[1], b2 = bias[2];

    const int t = threadIdx.x;
    const f32x4* __restrict__ xin = reinterpret_cast<const f32x4*>(x);
    f32x4* __restrict__ xout      = reinterpret_cast<f32x4*>(out);

    for (long long tile = blockIdx.x; tile < ntiles; tile += gridDim.x) {
        const long long base = tile * TILE_F4;

        // Compute-friendly load: thread owns 3 consecutive float4 = 4 points.
        f32x4 v0 = xin[base + 3 * t + 0];
        f32x4 v1 = xin[base + 3 * t + 1];
        f32x4 v2 = xin[base + 3 * t + 2];

        float p0x = v0.x, p0y = v0.y, p0z = v0.z;
        float p1x = v0.w, p1y = v1.x, p1z = v1.y;
        float p2x = v1.z, p2y = v1.w, p2z = v2.x;
        float p3x = v2.y, p3y = v2.z, p3z = v2.w;

        float o0x = fmaf(p0x, w00, fmaf(p0y, w10, fmaf(p0z, w20, b0)));
        float o0y = fmaf(p0x, w01, fmaf(p0y, w11, fmaf(p0z, w21, b1)));
        float o0z = fmaf(p0x, w02, fmaf(p0y, w12, fmaf(p0z, w22, b2)));

        float o1x = fmaf(p1x, w00, fmaf(p1y, w10, fmaf(p1z, w20, b0)));
        float o1y = fmaf(p1x, w01, fmaf(p1y, w11, fmaf(p1z, w21, b1)));
        float o1z = fmaf(p1x, w02, fmaf(p1y, w12, fmaf(p1z, w22, b2)));

        float o2x = fmaf(p2x, w00, fmaf(p2y, w10, fmaf(p2z, w20, b0)));
        float o2y = fmaf(p2x, w01, fmaf(p2y, w11, fmaf(p2z, w21, b1)));
        float o2z = fmaf(p2x, w02, fmaf(p2y, w12, fmaf(p2z, w22, b2)));

        float o3x = fmaf(p3x, w00, fmaf(p3y, w10, fmaf(p3z, w20, b0)));
        float o3y = fmaf(p3x, w01, fmaf(p3y, w11, fmaf(p3z, w21, b1)));
        float o3z = fmaf(p3x, w02, fmaf(p3y, w12, fmaf(p3z, w22, b2)));

        lds[3 * t + 0] = f32x4{o0x, o0y, o0z, o1x};
        lds[3 * t + 1] = f32x4{o1y, o1z, o2x, o2y};
        lds[3 * t + 2] = f32x4{o2z, o3x, o3y, o3z};

        __syncthreads();

        // Wave-contiguous nt stores: each instruction writes 64 lanes x 16 B
        // = 1 KB of consecutive, full 64B lines -> no write amplification.
        f32x4 s0 = lds[t];
        f32x4 s1 = lds[TPB + t];
        f32x4 s2 = lds[2 * TPB + t];
        __builtin_nontemporal_store(s0, &xout[base + t]);
        __builtin_nontemporal_store(s1, &xout[base + TPB + t]);
        __builtin_nontemporal_store(s2, &xout[base + 2 * TPB + t]);

        __syncthreads();   // protect lds before next iteration overwrites
    }

    // Scalar tail for points beyond full tiles (empty for the bench shape:
    // 8388608 points = 8192 tiles exactly).
    const long long donePts = ntiles * (TILE_F4 * 4LL / 3LL);
    for (long long p = donePts + (long long)blockIdx.x * TPB + t;
         p < npoints; p += (long long)gridDim.x * TPB) {
        float px = x[p * 3 + 0], py = x[p * 3 + 1], pz = x[p * 3 + 2];
        out[p * 3 + 0] = fmaf(px, w00, fmaf(py, w10, fmaf(pz, w20, b0)));
        out[p * 3 + 1] = fmaf(px, w01, fmaf(py, w11, fmaf(pz, w21, b1)));
        out[p * 3 + 2] = fmaf(px, w02, fmaf(py, w12, fmaf(pz, w22, b2)));
    }
}

extern "C" void kernel_launch(void* const* d_in, const int* in_sizes, int n_in,
                              void* d_out, int out_size, void* d_ws, size_t ws_size,
                              hipStream_t stream) {
    const float* x    = (const float*)d_in[0];
    const float* W    = (const float*)d_in[1];
    const float* bias = (const float*)d_in[2];
    float* out        = (float*)d_out;

    const long long n       = (long long)in_sizes[0];  // total floats in x
    const long long npoints = n / 3;
    const long long totalF4 = n / 4;                   // full float4s
    const long long ntiles  = totalF4 / TILE_F4;

    long long want = ntiles < 2048 ? (ntiles > 0 ? ntiles : 1) : 2048;
    int grid = (int)want;

    affine3_kernel<<<grid, TPB, 0, stream>>>(x, W, bias, out, ntiles, npoints);
}